// Round 3
// baseline (386.333 us; speedup 1.0000x reference)
//
#include <hip/hip_runtime.h>

// cReLU_percent: x (32,128,112,112) fp32. Per pixel (n,h,w): keep channel
// values >= the 64th-largest across C=128, then ReLU; zero the rest.
//
// R3: lane-QUAD split (4 lanes/pixel, 32 channels each) to get under the
// VGPR=64 occupancy cliff (8 waves/SIMD vs 4 at VGPR=100 in R2).
//  - Odd lanes of each quad store NEGATED values -> all lanes run the same
//    ascending bitonic-32 (descending sort for free, no divergence).
//  - Lane-pair merge (bitonic j=32 stage) via shfl_xor(1); the negated domain
//    makes it the uniform op v[i] = fmin(v[i], -recv) (neg = free modifier).
//  - 5-stage intra-lane bitonic merge -> each pair holds a sorted 64-run
//    (even lane: A[0..31] asc; odd lane: -(A[63-i]) i.e. upper half desc).
//  - Cross-pair bitonic split via shfl_xor(3): thr = min_u max(A[u],B[63-u]);
//    descending storage absorbs the 63-u reversal -> straight slot exchange.
//  - asm memory clobber forces the epilogue to RE-READ x (L2/L3-hot) instead
//    of keeping 32 originals live (+32 VGPRs would halve occupancy).

#define CC   128
#define HWSZ 12544   // 112*112; quads never straddle the n boundary

__device__ __forceinline__ void bitonic32(float v[32]) {
  #pragma unroll
  for (int k = 2; k <= 32; k <<= 1) {
    #pragma unroll
    for (int j = k >> 1; j > 0; j >>= 1) {
      #pragma unroll
      for (int i = 0; i < 32; ++i) {
        int l = i ^ j;
        if (l > i) {
          float lo = fminf(v[i], v[l]);
          float hi = fmaxf(v[i], v[l]);
          bool up = ((i & k) == 0);   // compile-time after unroll
          v[i] = up ? lo : hi;
          v[l] = up ? hi : lo;
        }
      }
    }
  }
}

__global__ __launch_bounds__(256) void crelu_pct_kernel(
    const float* __restrict__ x, float* __restrict__ out) {
  const int t = blockIdx.x * blockDim.x + threadIdx.x;
  const int q = t >> 2;   // pixel index (n*HWSZ + p)
  const int s = t & 3;    // channel group: channels [s*32, s*32+32)
  const int n = q / HWSZ;
  const int p = q - n * HWSZ;
  const size_t base = (size_t)n * ((size_t)CC * HWSZ) + (size_t)p
                    + (size_t)(s << 5) * HWSZ;
  const float* xp = x + base;
  float*       op = out + base;

  const unsigned smask = (s & 1) ? 0x80000000u : 0u;   // odd lanes: negate
  const unsigned omask = smask ^ 0x80000000u;          // partner's sign

  // ---- load 32 channels, sign-flip odd lanes, ascending bitonic-32 ----
  float v[32];
  #pragma unroll
  for (int c = 0; c < 32; ++c) {
    float w = xp[(size_t)c * HWSZ];
    v[c] = __uint_as_float(__float_as_uint(w) ^ smask);
  }
  bitonic32(v);   // stored-domain ascending (odd lanes: true-value descending)

  // ---- pair merge, bitonic stage j=32, via shfl_xor(1) ----
  // even lane keeps lower half (true domain); odd keeps upper half (negated).
  // Both reduce to the same expression in stored domain.
  #pragma unroll
  for (int i = 0; i < 32; ++i) {
    float r = __shfl_xor(v[i], 1, 64);
    v[i] = fminf(v[i], -r);
  }

  // ---- intra-lane bitonic merge (j=16..1), ascending in stored domain ----
  #pragma unroll
  for (int j = 16; j > 0; j >>= 1) {
    #pragma unroll
    for (int i = 0; i < 32; ++i) {
      int l = i ^ j;
      if (l > i) {
        float lo = fminf(v[i], v[l]);
        float hi = fmaxf(v[i], v[l]);
        v[i] = lo;
        v[l] = hi;
      }
    }
  }

  // Force the epilogue to reload x rather than carry 32 originals in VGPRs.
  asm volatile("" ::: "memory");

  // ---- cross-pair split: thr = min_u max(A[u], B[63-u]), partner = ^3 ----
  float acc = __builtin_inff();
  #pragma unroll
  for (int u = 0; u < 32; ++u) {
    float r = __shfl_xor(v[u], 3, 64);
    float mine  = __uint_as_float(__float_as_uint(v[u]) ^ smask);  // true val
    float other = __uint_as_float(__float_as_uint(r)    ^ omask);  // true val
    acc = fminf(acc, fmaxf(mine, other));
  }
  // lanes {0,3} hold min over u in [0,31], lanes {1,2} over [32,63]
  const float thr = fminf(acc, __shfl_xor(acc, 1, 64));

  // ---- re-read originals (L2/L3-hot), apply mask + ReLU, store ----
  #pragma unroll
  for (int c = 0; c < 32; ++c) {
    float w = xp[(size_t)c * HWSZ];
    op[(size_t)c * HWSZ] = (w >= thr && w > 0.0f) ? w : 0.0f;
  }
}

extern "C" void kernel_launch(void* const* d_in, const int* in_sizes, int n_in,
                              void* d_out, int out_size, void* d_ws, size_t ws_size,
                              hipStream_t stream) {
  const float* x = (const float*)d_in[0];
  float* out = (float*)d_out;
  const int npix = in_sizes[0] / CC;        // 401408
  const int nthreads = npix * 4;            // 1605632
  const int block = 256;
  const int grid = nthreads / block;        // 6272 exactly
  crelu_pct_kernel<<<grid, block, 0, stream>>>(x, out);
}